// Round 8
// baseline (78.818 us; speedup 1.0000x reference)
//
#include <hip/hip_runtime.h>
#include <stdint.h>

#define BATCH 16
#define NPTS  4096
#define TOT   (BATCH * NPTS)     // 65536 points per tensor
#define TWOTOT (2 * TOT)

typedef float f2 __attribute__((ext_vector_type(2)));
typedef float f4 __attribute__((ext_vector_type(4)));
typedef uint32_t u32;
typedef u32 u32x4 __attribute__((ext_vector_type(4)));

// ---- packed fp32 with op_sel word-broadcast (VOP3P), verified R4-R7 ----
#define PK_Z(t, p, qzw) \
    asm("v_pk_fma_f32 %0, %1, %2, %2 op_sel:[0,0,1] op_sel_hi:[1,0,1]" \
        : "=v"(t) : "v"(p), "v"(qzw))
#define PK_HI(t, p, q) \
    asm("v_pk_fma_f32 %0, %1, %2, %0 op_sel:[0,1,0] op_sel_hi:[1,1,1]" \
        : "+v"(t) : "v"(p), "v"(q))
#define PK_LO(t, p, q) \
    asm("v_pk_fma_f32 %0, %1, %2, %0 op_sel:[0,0,0] op_sel_hi:[1,0,1]" \
        : "+v"(t) : "v"(p), "v"(q))
#define MIN3(acc, u, v) \
    asm("v_min3_f32 %0, %1, %2, %0" : "+v"(acc) : "v"(u), "v"(v))

// distance chains for one Q point against BOTH packed P pairs
#define QD(t0, t1, qv)                                          \
    do {                                                        \
        f2 _qxy = __builtin_shufflevector(qv, qv, 0, 1);        \
        f2 _qzw = __builtin_shufflevector(qv, qv, 2, 3);        \
        PK_Z(t0, pz2a, _qzw); PK_HI(t0, py2a, _qxy); PK_LO(t0, px2a, _qxy); \
        PK_Z(t1, pz2b, _qzw); PK_HI(t1, py2b, _qxy); PK_LO(t1, px2b, _qxy); \
    } while (0)

// 2 Q points vs the thread's 4 P points: 12 pk_fma + 4 min3
#define COMP2(qA, qB)                                           \
    do {                                                        \
        f2 tA0, tA1, tB0, tB1;                                  \
        QD(tA0, tA1, qA); QD(tB0, tB1, qB);                     \
        MIN3(acc0, tA0.x, tB0.x); MIN3(acc1, tA0.y, tB0.y);     \
        MIN3(acc2, tA1.x, tB1.x); MIN3(acc3, tA1.y, tB1.y);     \
    } while (0)

// scalar-addressed broadcast load: SRSRC (SGPR quad) + soffset(SGPR) + imm
#define BLOAD(dst, imm) \
    asm volatile("buffer_load_dwordx4 %0, off, %1, %2 offset:" imm \
                 : "=v"(dst) : "s"(rsrc), "s"(soff))

#define SBUMP(n) \
    asm volatile("s_add_u32 %0, %0, " n : "+s"(soff) :: "scc")

// counted wait for the oldest 2 loads; ties both slots so dependent math
// can't hoist; sched_barrier fences the scheduler (rule #18).
#define WAIT2(cnt, qa, qb)                                      \
    do {                                                        \
        asm volatile("s_waitcnt vmcnt(" cnt ")"                 \
                     : "+v"(qa), "+v"(qb));                     \
        __builtin_amdgcn_sched_barrier(0);                      \
    } while (0)

// steady-state pipeline step: wait oldest 2, compute, reload those slots
#define STEP(qa, qb, immA, immB)                                \
    do {                                                        \
        WAIT2("14", qa, qb);                                    \
        COMP2(qa, qb);                                          \
        BLOAD(qa, immA); BLOAD(qb, immB);                       \
    } while (0)

#define STEPD(cnt, qa, qb)  do { WAIT2(cnt, qa, qb); COMP2(qa, qb); } while (0)

// Pack {x, y, z, |q|^2} AoS float4 per point; also zero the output scalar.
// pk layout: [2][BATCH][NPTS] f4 ; slot 0 = x tensor, slot 1 = y tensor.
__global__ __launch_bounds__(256) void pack_kernel(const float* __restrict__ x,
                                                   const float* __restrict__ y,
                                                   f4* __restrict__ pk,
                                                   float* __restrict__ out) {
    int idx = blockIdx.x * 256 + threadIdx.x;       // 0 .. 2*TOT-1
    if (idx == 0) out[0] = 0.0f;
    const float* src = (idx < TOT) ? x : y;
    int r = (idx < TOT) ? idx : (idx - TOT);
    float a = src[r * 3 + 0];
    float b = src[r * 3 + 1];
    float c = src[r * 3 + 2];
    f4 v = {a, b, c, fmaf(a, a, fmaf(b, b, c * c))};
    pk[idx] = v;
}

// Pass 1: each thread owns 4 consecutive P points (2 packed pairs); scans its
// Q segment through a 16-slot rotating register pipeline with fine-grained
// vmcnt(14) waits (only the oldest 2 loads per step). Scalar Q addressing.
template <int QSEGT>
__global__ __launch_bounds__(256) void chamfer_pass1(const f4* __restrict__ pk,
                                                     float* __restrict__ part) {
    constexpr int QLENT = NPTS / QSEGT;
    constexpr int NITER = QLENT / 16 - 1;     // full pipeline iterations

    int qseg  = blockIdx.x & (QSEGT - 1);
    int chunk = blockIdx.x / QSEGT;           // 128 chunks of 1024 P points

    // block-uniform (from blockIdx only) -> SALU
    int grp   = chunk >> 2;                   // dir*16 + batch
    int dir   = grp >> 4;
    int bb    = grp & 15;

    int pidx0 = chunk * 1024 + threadIdx.x * 4;

    f4 p0 = pk[pidx0 + 0];
    f4 p1 = pk[pidx0 + 1];
    f4 p2 = pk[pidx0 + 2];
    f4 p3 = pk[pidx0 + 3];
    f2 px2a = {-2.0f * p0.x, -2.0f * p1.x}, px2b = {-2.0f * p2.x, -2.0f * p3.x};
    f2 py2a = {-2.0f * p0.y, -2.0f * p1.y}, py2b = {-2.0f * p2.y, -2.0f * p3.y};
    f2 pz2a = {-2.0f * p0.z, -2.0f * p1.z}, pz2b = {-2.0f * p2.z, -2.0f * p3.z};
    // pin P setup (and its load drain) above the pipeline prologue
    asm volatile("" :: "v"(px2a), "v"(py2a), "v"(pz2a),
                       "v"(px2b), "v"(py2b), "v"(pz2b));
    __builtin_amdgcn_sched_barrier(0);

    // SRSRC for the Q segment; readfirstlane pins base words to SGPRs
    union { const f4* p; u32 w[2]; } pu;
    pu.p = pk + (1 - dir) * TOT + bb * NPTS + qseg * QLENT;
    u32 w0 = __builtin_amdgcn_readfirstlane(pu.w[0]);
    u32 w1 = __builtin_amdgcn_readfirstlane(pu.w[1]);
    u32x4 rsrc = { w0, w1, (u32)(QLENT * 16), 0x00020000u };
    u32 soff = 0;

    float acc0 = 3.4e38f, acc1 = 3.4e38f, acc2 = 3.4e38f, acc3 = 3.4e38f;

    f4 s0, s1, s2, s3, s4, s5, s6, s7, s8, s9, s10, s11, s12, s13, s14, s15;
    // prologue: fill all 16 slots (Q[0..15]), advance soff to Q[16]
    BLOAD(s0, "0");    BLOAD(s1, "16");   BLOAD(s2, "32");   BLOAD(s3, "48");
    BLOAD(s4, "64");   BLOAD(s5, "80");   BLOAD(s6, "96");   BLOAD(s7, "112");
    BLOAD(s8, "128");  BLOAD(s9, "144");  BLOAD(s10, "160"); BLOAD(s11, "176");
    BLOAD(s12, "192"); BLOAD(s13, "208"); BLOAD(s14, "224"); BLOAD(s15, "240");
    SBUMP("256");

    #pragma unroll 1
    for (int it = 0; it < NITER; ++it) {
        STEP(s0,  s1,  "0",   "16");
        STEP(s2,  s3,  "32",  "48");
        STEP(s4,  s5,  "64",  "80");
        STEP(s6,  s7,  "96",  "112");
        STEP(s8,  s9,  "128", "144");
        STEP(s10, s11, "160", "176");
        STEP(s12, s13, "192", "208");
        STEP(s14, s15, "224", "240");
        SBUMP("256");
    }
    // drain: consume the last 16 slots, no reloads
    STEPD("14", s0,  s1);
    STEPD("12", s2,  s3);
    STEPD("10", s4,  s5);
    STEPD("8",  s6,  s7);
    STEPD("6",  s8,  s9);
    STEPD("4",  s10, s11);
    STEPD("2",  s12, s13);
    STEPD("0",  s14, s15);

    f4 res = {acc0, acc1, acc2, acc3};
    *(f4*)(part + qseg * TWOTOT + pidx0) = res;   // coalesced 16B store
}

// Pass 2: 4 points per thread, f4 loads of the partials, add |p|^2,
// block-reduce, one atomic per block.
__global__ __launch_bounds__(256) void chamfer_pass2(const f4* __restrict__ part4,
                                                     const float* __restrict__ pkf,
                                                     float* __restrict__ out,
                                                     int nseg) {
    int t4  = blockIdx.x * 256 + threadIdx.x;     // 0..TWOTOT/4-1
    f4 m = part4[t4];
    for (int s = 1; s < nseg; ++s) {
        f4 v = part4[s * (TWOTOT / 4) + t4];
        m.x = fminf(m.x, v.x); m.y = fminf(m.y, v.y);
        m.z = fminf(m.z, v.z); m.w = fminf(m.w, v.w);
    }
    int gid = t4 * 4;
    float r = (m.x + pkf[(gid + 0) * 4 + 3]) + (m.y + pkf[(gid + 1) * 4 + 3])
            + (m.z + pkf[(gid + 2) * 4 + 3]) + (m.w + pkf[(gid + 3) * 4 + 3]);

    float s = r;
    #pragma unroll
    for (int off = 32; off; off >>= 1) s += __shfl_down(s, off);
    __shared__ float red[4];
    int lane = threadIdx.x & 63, wid = threadIdx.x >> 6;
    if (lane == 0) red[wid] = s;
    __syncthreads();
    if (threadIdx.x == 0) {
        float tot = (red[0] + red[1]) + (red[2] + red[3]);
        atomicAdd(out, tot * (1.0f / (float)TOT));
    }
}

// ---------------- fallback (no workspace): direct form ----------------
__global__ __launch_bounds__(256) void chamfer_direct(const float* __restrict__ x,
                                                      const float* __restrict__ y,
                                                      float* __restrict__ out) {
    int blk   = blockIdx.x;
    int dir   = blk >> 8;
    int t     = blk & 255;
    int b     = t >> 4;
    int chunk = t & 15;

    const float* __restrict__ P = (dir ? y : x) + (b * NPTS + chunk * 256) * 3;
    const float* __restrict__ Q = (dir ? x : y) + b * NPTS * 3;

    float px = P[threadIdx.x * 3 + 0];
    float py = P[threadIdx.x * 3 + 1];
    float pz = P[threadIdx.x * 3 + 2];

    float b0 = 3.4e38f, b1 = 3.4e38f, b2 = 3.4e38f, b3 = 3.4e38f;
    for (int j = 0; j < NPTS; j += 4) {
        #pragma unroll
        for (int u = 0; u < 4; ++u) {
            float dx = px - Q[(j + u) * 3 + 0];
            float dy = py - Q[(j + u) * 3 + 1];
            float dz = pz - Q[(j + u) * 3 + 2];
            float d  = fmaf(dx, dx, fmaf(dy, dy, dz * dz));
            if (u == 0) b0 = fminf(b0, d);
            if (u == 1) b1 = fminf(b1, d);
            if (u == 2) b2 = fminf(b2, d);
            if (u == 3) b3 = fminf(b3, d);
        }
    }
    float best = fminf(fminf(b0, b1), fminf(b2, b3));

    float v = best;
    #pragma unroll
    for (int off = 32; off; off >>= 1) v += __shfl_down(v, off);
    __shared__ float red[4];
    int lane = threadIdx.x & 63, wid = threadIdx.x >> 6;
    if (lane == 0) red[wid] = v;
    __syncthreads();
    if (threadIdx.x == 0) {
        float s = (red[0] + red[1]) + (red[2] + red[3]);
        atomicAdd(out, s * (1.0f / (float)TOT));
    }
}

__global__ void zero_kernel(float* out) { out[0] = 0.0f; }

extern "C" void kernel_launch(void* const* d_in, const int* in_sizes, int n_in,
                              void* d_out, int out_size, void* d_ws, size_t ws_size,
                              hipStream_t stream) {
    const float* x = (const float*)d_in[0];
    const float* y = (const float*)d_in[1];
    float* out = (float*)d_out;

    size_t pk_bytes = (size_t)TWOTOT * 4 * sizeof(float);         // 2 MiB
    auto part_bytes = [&](int qseg) { return (size_t)qseg * TWOTOT * sizeof(float); };

    if (ws_size >= pk_bytes + part_bytes(16)) {
        // QSEG = 16 : grid 2048 (8 blocks/CU), part 8 MiB
        float* pkf  = (float*)d_ws;
        float* part = (float*)((char*)d_ws + pk_bytes);
        hipLaunchKernelGGL(pack_kernel, dim3(TWOTOT / 256), dim3(256), 0, stream,
                           x, y, (f4*)pkf, out);
        hipLaunchKernelGGL((chamfer_pass1<16>), dim3(128 * 16), dim3(256), 0, stream,
                           (const f4*)pkf, part);
        hipLaunchKernelGGL(chamfer_pass2, dim3(TWOTOT / 4 / 256), dim3(256), 0, stream,
                           (const f4*)part, pkf, out, 16);
    } else if (ws_size >= pk_bytes + part_bytes(8)) {
        // QSEG = 8 : grid 1024, part 4 MiB
        float* pkf  = (float*)d_ws;
        float* part = (float*)((char*)d_ws + pk_bytes);
        hipLaunchKernelGGL(pack_kernel, dim3(TWOTOT / 256), dim3(256), 0, stream,
                           x, y, (f4*)pkf, out);
        hipLaunchKernelGGL((chamfer_pass1<8>), dim3(128 * 8), dim3(256), 0, stream,
                           (const f4*)pkf, part);
        hipLaunchKernelGGL(chamfer_pass2, dim3(TWOTOT / 4 / 256), dim3(256), 0, stream,
                           (const f4*)part, pkf, out, 8);
    } else if (ws_size >= pk_bytes + part_bytes(4)) {
        // QSEG = 4 : grid 512, part 2 MiB
        float* pkf  = (float*)d_ws;
        float* part = (float*)((char*)d_ws + pk_bytes);
        hipLaunchKernelGGL(pack_kernel, dim3(TWOTOT / 256), dim3(256), 0, stream,
                           x, y, (f4*)pkf, out);
        hipLaunchKernelGGL((chamfer_pass1<4>), dim3(128 * 4), dim3(256), 0, stream,
                           (const f4*)pkf, part);
        hipLaunchKernelGGL(chamfer_pass2, dim3(TWOTOT / 4 / 256), dim3(256), 0, stream,
                           (const f4*)part, pkf, out, 4);
    } else {
        hipLaunchKernelGGL(zero_kernel, dim3(1), dim3(1), 0, stream, out);
        hipLaunchKernelGGL(chamfer_direct, dim3(512), dim3(256), 0, stream, x, y, out);
    }
}

// Round 9
// 57.214 us; speedup vs baseline: 1.3776x; 1.3776x over previous
//
#include <hip/hip_runtime.h>
#include <stdint.h>

#define BATCH 16
#define NPTS  4096
#define TOT   (BATCH * NPTS)     // 65536 points per tensor
#define TWOTOT (2 * TOT)

typedef float f2 __attribute__((ext_vector_type(2)));
typedef float f4 __attribute__((ext_vector_type(4)));
typedef uint32_t u32;
typedef unsigned long long u64;

// ---- packed fp32, q operand in SGPRs (1 scalar source per VOP3P) ----
// t = { p.lo*q.z + q.w , p.hi*q.z + q.w }   (qzw = SGPR pair {z,w})
#define PK_Zs(t, p, qzw) \
    asm("v_pk_fma_f32 %0, %1, %2, %2 op_sel:[0,0,1] op_sel_hi:[1,0,1]" \
        : "=v"(t) : "v"(p), "s"(qzw))
#define PK_HIs(t, p, qxy) \
    asm("v_pk_fma_f32 %0, %1, %2, %0 op_sel:[0,1,0] op_sel_hi:[1,1,1]" \
        : "+v"(t) : "v"(p), "s"(qxy))
#define PK_LOs(t, p, qxy) \
    asm("v_pk_fma_f32 %0, %1, %2, %0 op_sel:[0,0,0] op_sel_hi:[1,0,1]" \
        : "+v"(t) : "v"(p), "s"(qxy))
#define MIN3(acc, u, v) \
    asm("v_min3_f32 %0, %1, %2, %0" : "+v"(acc) : "v"(u), "v"(v))

// distance chains for one SGPR-resident Q point against both packed P pairs
#define QDS(t0, t1, qq)                                         \
    do {                                                        \
        f2 _qxy = {qq.x, qq.y};   /* even-aligned SGPR pair */  \
        f2 _qzw = {qq.z, qq.w};                                 \
        PK_Zs(t0, pz2a, _qzw); PK_HIs(t0, py2a, _qxy); PK_LOs(t0, px2a, _qxy); \
        PK_Zs(t1, pz2b, _qzw); PK_HIs(t1, py2b, _qxy); PK_LOs(t1, px2b, _qxy); \
    } while (0)

// 2 Q points vs the thread's 4 P points: 12 pk_fma + 4 min3
#define COMP2S(qA, qB)                                          \
    do {                                                        \
        f2 tA0, tA1, tB0, tB1;                                  \
        QDS(tA0, tA1, qA); QDS(tB0, tB1, qB);                   \
        MIN3(acc0, tA0.x, tB0.x); MIN3(acc1, tA0.y, tB0.y);     \
        MIN3(acc2, tA1.x, tB1.x); MIN3(acc3, tA1.y, tB1.y);     \
    } while (0)

#define COMP8S(q0, q1, q2, q3, q4, q5, q6, q7)                  \
    do { COMP2S(q0, q1); COMP2S(q2, q3); COMP2S(q4, q5); COMP2S(q6, q7); } while (0)

// one scalar load of one Q point (16B) at qb + imm
#define SL(dst, imm) \
    asm volatile("s_load_dwordx4 %0, %1, " imm : "=s"(dst) : "s"(qb))

// issue one 8-point chunk (128B via 8 s_load_dwordx4), bump base, pin issue pt
#define SLOAD8(n0, n1, n2, n3, n4, n5, n6, n7)                  \
    do {                                                        \
        SL(n0, "0x0");  SL(n1, "0x10"); SL(n2, "0x20"); SL(n3, "0x30"); \
        SL(n4, "0x40"); SL(n5, "0x50"); SL(n6, "0x60"); SL(n7, "0x70"); \
        qb += 128;                                              \
        __builtin_amdgcn_sched_barrier(0);                      \
    } while (0)

// drain SMEM (out-of-order completion -> only lgkmcnt(0) is safe); ties the
// chunk so dependent math can't hoist; sched_barrier fences (rule #18).
#define LGKMW8(a0, a1, a2, a3, a4, a5, a6, a7)                  \
    do {                                                        \
        asm volatile("s_waitcnt lgkmcnt(0)"                     \
            : "+s"(a0), "+s"(a1), "+s"(a2), "+s"(a3),           \
              "+s"(a4), "+s"(a5), "+s"(a6), "+s"(a7));          \
        __builtin_amdgcn_sched_barrier(0);                      \
    } while (0)

// Pack {x, y, z, |q|^2} AoS float4 per point; also zero the output scalar.
// pk layout: [2][BATCH][NPTS] f4 ; slot 0 = x tensor, slot 1 = y tensor.
__global__ __launch_bounds__(256) void pack_kernel(const float* __restrict__ x,
                                                   const float* __restrict__ y,
                                                   f4* __restrict__ pk,
                                                   float* __restrict__ out) {
    int idx = blockIdx.x * 256 + threadIdx.x;       // 0 .. 2*TOT-1
    if (idx == 0) out[0] = 0.0f;
    const float* src = (idx < TOT) ? x : y;
    int r = (idx < TOT) ? idx : (idx - TOT);
    float a = src[r * 3 + 0];
    float b = src[r * 3 + 1];
    float c = src[r * 3 + 2];
    f4 v = {a, b, c, fmaf(a, a, fmaf(b, b, c * c))};
    pk[idx] = v;
}

// Pass 1: each thread owns 4 consecutive P points (2 packed register pairs);
// Q points stream through SGPRs via s_load_dwordx4 (fetched ONCE per wave,
// not replicated 64x like VMEM broadcast). Double-banked 8-point chunks:
// issue next chunk -> compute current (224 cy) -> lgkmcnt(0).
template <int QSEGT>
__global__ __launch_bounds__(256) void chamfer_pass1(const f4* __restrict__ pk,
                                                     float* __restrict__ part) {
    constexpr int QLENT  = NPTS / QSEGT;
    constexpr int CHUNKS = QLENT / 8;         // 8-Q chunks per segment (even)

    int qseg  = blockIdx.x & (QSEGT - 1);
    int chunk = blockIdx.x / QSEGT;           // 128 chunks of 1024 P points

    // block-uniform (from blockIdx only) -> SALU
    int grp   = chunk >> 2;                   // dir*16 + batch
    int dir   = grp >> 4;
    int bb    = grp & 15;

    int pidx0 = chunk * 1024 + threadIdx.x * 4;

    f4 p0 = pk[pidx0 + 0];
    f4 p1 = pk[pidx0 + 1];
    f4 p2 = pk[pidx0 + 2];
    f4 p3 = pk[pidx0 + 3];
    f2 px2a = {-2.0f * p0.x, -2.0f * p1.x}, px2b = {-2.0f * p2.x, -2.0f * p3.x};
    f2 py2a = {-2.0f * p0.y, -2.0f * p1.y}, py2b = {-2.0f * p2.y, -2.0f * p3.y};
    f2 pz2a = {-2.0f * p0.z, -2.0f * p1.z}, pz2b = {-2.0f * p2.z, -2.0f * p3.z};
    asm volatile("" :: "v"(px2a), "v"(py2a), "v"(pz2a),
                       "v"(px2b), "v"(py2b), "v"(pz2b));
    __builtin_amdgcn_sched_barrier(0);

    // uniform 64-bit Q base in SGPRs
    union { const f4* p; u32 w[2]; } pu;
    pu.p = pk + (1 - dir) * TOT + bb * NPTS + qseg * QLENT;
    u32 w0 = __builtin_amdgcn_readfirstlane(pu.w[0]);
    u32 w1 = __builtin_amdgcn_readfirstlane(pu.w[1]);
    u64 qb = ((u64)w1 << 32) | w0;

    float acc0 = 3.4e38f, acc1 = 3.4e38f, acc2 = 3.4e38f, acc3 = 3.4e38f;

    f4 c0, c1, c2, c3, c4, c5, c6, c7;        // current bank (SGPRs)
    f4 n0, n1, n2, n3, n4, n5, n6, n7;        // next bank (SGPRs)

    SLOAD8(c0, c1, c2, c3, c4, c5, c6, c7);   // chunk 0
    LGKMW8(c0, c1, c2, c3, c4, c5, c6, c7);

    #pragma unroll 1
    for (int it = 0; it < (CHUNKS - 2) / 2; ++it) {
        SLOAD8(n0, n1, n2, n3, n4, n5, n6, n7);      // chunk 2it+1
        COMP8S(c0, c1, c2, c3, c4, c5, c6, c7);      // chunk 2it   (224 cy)
        LGKMW8(n0, n1, n2, n3, n4, n5, n6, n7);
        SLOAD8(c0, c1, c2, c3, c4, c5, c6, c7);      // chunk 2it+2
        COMP8S(n0, n1, n2, n3, n4, n5, n6, n7);      // chunk 2it+1
        LGKMW8(c0, c1, c2, c3, c4, c5, c6, c7);
    }
    // loaded through chunk CHUNKS-2 (in c); consume last two chunks
    SLOAD8(n0, n1, n2, n3, n4, n5, n6, n7);          // chunk CHUNKS-1
    COMP8S(c0, c1, c2, c3, c4, c5, c6, c7);          // chunk CHUNKS-2
    LGKMW8(n0, n1, n2, n3, n4, n5, n6, n7);
    COMP8S(n0, n1, n2, n3, n4, n5, n6, n7);          // chunk CHUNKS-1

    f4 res = {acc0, acc1, acc2, acc3};
    *(f4*)(part + qseg * TWOTOT + pidx0) = res;      // coalesced 16B store
}

// Pass 2: 4 points per thread, f4 loads of the partials, add |p|^2,
// block-reduce, one atomic per block.
__global__ __launch_bounds__(256) void chamfer_pass2(const f4* __restrict__ part4,
                                                     const float* __restrict__ pkf,
                                                     float* __restrict__ out,
                                                     int nseg) {
    int t4  = blockIdx.x * 256 + threadIdx.x;     // 0..TWOTOT/4-1
    f4 m = part4[t4];
    for (int s = 1; s < nseg; ++s) {
        f4 v = part4[s * (TWOTOT / 4) + t4];
        m.x = fminf(m.x, v.x); m.y = fminf(m.y, v.y);
        m.z = fminf(m.z, v.z); m.w = fminf(m.w, v.w);
    }
    int gid = t4 * 4;
    float r = (m.x + pkf[(gid + 0) * 4 + 3]) + (m.y + pkf[(gid + 1) * 4 + 3])
            + (m.z + pkf[(gid + 2) * 4 + 3]) + (m.w + pkf[(gid + 3) * 4 + 3]);

    float s = r;
    #pragma unroll
    for (int off = 32; off; off >>= 1) s += __shfl_down(s, off);
    __shared__ float red[4];
    int lane = threadIdx.x & 63, wid = threadIdx.x >> 6;
    if (lane == 0) red[wid] = s;
    __syncthreads();
    if (threadIdx.x == 0) {
        float tot = (red[0] + red[1]) + (red[2] + red[3]);
        atomicAdd(out, tot * (1.0f / (float)TOT));
    }
}

// ---------------- fallback (no workspace): direct form ----------------
__global__ __launch_bounds__(256) void chamfer_direct(const float* __restrict__ x,
                                                      const float* __restrict__ y,
                                                      float* __restrict__ out) {
    int blk   = blockIdx.x;
    int dir   = blk >> 8;
    int t     = blk & 255;
    int b     = t >> 4;
    int chunk = t & 15;

    const float* __restrict__ P = (dir ? y : x) + (b * NPTS + chunk * 256) * 3;
    const float* __restrict__ Q = (dir ? x : y) + b * NPTS * 3;

    float px = P[threadIdx.x * 3 + 0];
    float py = P[threadIdx.x * 3 + 1];
    float pz = P[threadIdx.x * 3 + 2];

    float b0 = 3.4e38f, b1 = 3.4e38f, b2 = 3.4e38f, b3 = 3.4e38f;
    for (int j = 0; j < NPTS; j += 4) {
        #pragma unroll
        for (int u = 0; u < 4; ++u) {
            float dx = px - Q[(j + u) * 3 + 0];
            float dy = py - Q[(j + u) * 3 + 1];
            float dz = pz - Q[(j + u) * 3 + 2];
            float d  = fmaf(dx, dx, fmaf(dy, dy, dz * dz));
            if (u == 0) b0 = fminf(b0, d);
            if (u == 1) b1 = fminf(b1, d);
            if (u == 2) b2 = fminf(b2, d);
            if (u == 3) b3 = fminf(b3, d);
        }
    }
    float best = fminf(fminf(b0, b1), fminf(b2, b3));

    float v = best;
    #pragma unroll
    for (int off = 32; off; off >>= 1) v += __shfl_down(v, off);
    __shared__ float red[4];
    int lane = threadIdx.x & 63, wid = threadIdx.x >> 6;
    if (lane == 0) red[wid] = v;
    __syncthreads();
    if (threadIdx.x == 0) {
        float s = (red[0] + red[1]) + (red[2] + red[3]);
        atomicAdd(out, s * (1.0f / (float)TOT));
    }
}

__global__ void zero_kernel(float* out) { out[0] = 0.0f; }

extern "C" void kernel_launch(void* const* d_in, const int* in_sizes, int n_in,
                              void* d_out, int out_size, void* d_ws, size_t ws_size,
                              hipStream_t stream) {
    const float* x = (const float*)d_in[0];
    const float* y = (const float*)d_in[1];
    float* out = (float*)d_out;

    size_t pk_bytes = (size_t)TWOTOT * 4 * sizeof(float);         // 2 MiB
    auto part_bytes = [&](int qseg) { return (size_t)qseg * TWOTOT * sizeof(float); };

    if (ws_size >= pk_bytes + part_bytes(16)) {
        // QSEG = 16 : grid 2048 (8 blocks/CU), part 8 MiB
        float* pkf  = (float*)d_ws;
        float* part = (float*)((char*)d_ws + pk_bytes);
        hipLaunchKernelGGL(pack_kernel, dim3(TWOTOT / 256), dim3(256), 0, stream,
                           x, y, (f4*)pkf, out);
        hipLaunchKernelGGL((chamfer_pass1<16>), dim3(128 * 16), dim3(256), 0, stream,
                           (const f4*)pkf, part);
        hipLaunchKernelGGL(chamfer_pass2, dim3(TWOTOT / 4 / 256), dim3(256), 0, stream,
                           (const f4*)part, pkf, out, 16);
    } else if (ws_size >= pk_bytes + part_bytes(8)) {
        // QSEG = 8 : grid 1024, part 4 MiB
        float* pkf  = (float*)d_ws;
        float* part = (float*)((char*)d_ws + pk_bytes);
        hipLaunchKernelGGL(pack_kernel, dim3(TWOTOT / 256), dim3(256), 0, stream,
                           x, y, (f4*)pkf, out);
        hipLaunchKernelGGL((chamfer_pass1<8>), dim3(128 * 8), dim3(256), 0, stream,
                           (const f4*)pkf, part);
        hipLaunchKernelGGL(chamfer_pass2, dim3(TWOTOT / 4 / 256), dim3(256), 0, stream,
                           (const f4*)part, pkf, out, 8);
    } else if (ws_size >= pk_bytes + part_bytes(4)) {
        // QSEG = 4 : grid 512, part 2 MiB
        float* pkf  = (float*)d_ws;
        float* part = (float*)((char*)d_ws + pk_bytes);
        hipLaunchKernelGGL(pack_kernel, dim3(TWOTOT / 256), dim3(256), 0, stream,
                           x, y, (f4*)pkf, out);
        hipLaunchKernelGGL((chamfer_pass1<4>), dim3(128 * 4), dim3(256), 0, stream,
                           (const f4*)pkf, part);
        hipLaunchKernelGGL(chamfer_pass2, dim3(TWOTOT / 4 / 256), dim3(256), 0, stream,
                           (const f4*)part, pkf, out, 4);
    } else {
        hipLaunchKernelGGL(zero_kernel, dim3(1), dim3(1), 0, stream, out);
        hipLaunchKernelGGL(chamfer_direct, dim3(512), dim3(256), 0, stream, x, y, out);
    }
}

// Round 10
// 56.699 us; speedup vs baseline: 1.3901x; 1.0091x over previous
//
#include <hip/hip_runtime.h>
#include <stdint.h>

#define BATCH 16
#define NPTS  4096
#define TOT   (BATCH * NPTS)     // 65536 points per tensor
#define TWOTOT (2 * TOT)

typedef float f2 __attribute__((ext_vector_type(2)));
typedef float f4 __attribute__((ext_vector_type(4)));
typedef uint32_t u32;
typedef unsigned long long u64;

// ---- packed fp32, q operand in SGPRs (1 scalar source per VOP3P) ----
#define PK_Zs(t, p, qzw) \
    asm("v_pk_fma_f32 %0, %1, %2, %2 op_sel:[0,0,1] op_sel_hi:[1,0,1]" \
        : "=v"(t) : "v"(p), "s"(qzw))
#define PK_HIs(t, p, qxy) \
    asm("v_pk_fma_f32 %0, %1, %2, %0 op_sel:[0,1,0] op_sel_hi:[1,1,1]" \
        : "+v"(t) : "v"(p), "s"(qxy))
#define PK_LOs(t, p, qxy) \
    asm("v_pk_fma_f32 %0, %1, %2, %0 op_sel:[0,0,0] op_sel_hi:[1,0,1]" \
        : "+v"(t) : "v"(p), "s"(qxy))
#define MIN3(acc, u, v) \
    asm("v_min3_f32 %0, %1, %2, %0" : "+v"(acc) : "v"(u), "v"(v))

// distance chains for one SGPR-resident Q point against all 4 packed P pairs
#define QDS4(t0, t1, t2, t3, qq)                                \
    do {                                                        \
        f2 _qxy = {qq.x, qq.y};                                 \
        f2 _qzw = {qq.z, qq.w};                                 \
        PK_Zs(t0, pz2a, _qzw); PK_HIs(t0, py2a, _qxy); PK_LOs(t0, px2a, _qxy); \
        PK_Zs(t1, pz2b, _qzw); PK_HIs(t1, py2b, _qxy); PK_LOs(t1, px2b, _qxy); \
        PK_Zs(t2, pz2c, _qzw); PK_HIs(t2, py2c, _qxy); PK_LOs(t2, px2c, _qxy); \
        PK_Zs(t3, pz2d, _qzw); PK_HIs(t3, py2d, _qxy); PK_LOs(t3, px2d, _qxy); \
    } while (0)

// 2 Q points vs the thread's 8 P points: 24 pk_fma + 8 min3
#define COMP2S(qA, qB)                                          \
    do {                                                        \
        f2 A0, A1, A2, A3, B0, B1, B2, B3;                      \
        QDS4(A0, A1, A2, A3, qA); QDS4(B0, B1, B2, B3, qB);     \
        MIN3(acc0, A0.x, B0.x); MIN3(acc1, A0.y, B0.y);         \
        MIN3(acc2, A1.x, B1.x); MIN3(acc3, A1.y, B1.y);         \
        MIN3(acc4, A2.x, B2.x); MIN3(acc5, A2.y, B2.y);         \
        MIN3(acc6, A3.x, B3.x); MIN3(acc7, A3.y, B3.y);         \
    } while (0)

#define COMP8S(q0, q1, q2, q3, q4, q5, q6, q7)                  \
    do { COMP2S(q0, q1); COMP2S(q2, q3); COMP2S(q4, q5); COMP2S(q6, q7); } while (0)

// one scalar load of one Q point (16B) at qb + imm
#define SL(dst, imm) \
    asm volatile("s_load_dwordx4 %0, %1, " imm : "=s"(dst) : "s"(qb))

// issue one 8-point chunk (128B), bump base, pin issue point
#define SLOAD8(n0, n1, n2, n3, n4, n5, n6, n7)                  \
    do {                                                        \
        SL(n0, "0x0");  SL(n1, "0x10"); SL(n2, "0x20"); SL(n3, "0x30"); \
        SL(n4, "0x40"); SL(n5, "0x50"); SL(n6, "0x60"); SL(n7, "0x70"); \
        qb += 128;                                              \
        __builtin_amdgcn_sched_barrier(0);                      \
    } while (0)

// drain SMEM (OOO completion -> only lgkmcnt(0) safe); ties the chunk so
// dependent math can't hoist; sched_barrier fences (rule #18).
#define LGKMW8(a0, a1, a2, a3, a4, a5, a6, a7)                  \
    do {                                                        \
        asm volatile("s_waitcnt lgkmcnt(0)"                     \
            : "+s"(a0), "+s"(a1), "+s"(a2), "+s"(a3),           \
              "+s"(a4), "+s"(a5), "+s"(a6), "+s"(a7));          \
        __builtin_amdgcn_sched_barrier(0);                      \
    } while (0)

// Pack {x, y, z, |q|^2} AoS float4 per point; also zero the output scalar.
// pk layout: [2][BATCH][NPTS] f4 ; slot 0 = x tensor, slot 1 = y tensor.
__global__ __launch_bounds__(256) void pack_kernel(const float* __restrict__ x,
                                                   const float* __restrict__ y,
                                                   f4* __restrict__ pk,
                                                   float* __restrict__ out) {
    int idx = blockIdx.x * 256 + threadIdx.x;       // 0 .. 2*TOT-1
    if (idx == 0) out[0] = 0.0f;
    const float* src = (idx < TOT) ? x : y;
    int r = (idx < TOT) ? idx : (idx - TOT);
    float a = src[r * 3 + 0];
    float b = src[r * 3 + 1];
    float c = src[r * 3 + 2];
    f4 v = {a, b, c, fmaf(a, a, fmaf(b, b, c * c))};
    pk[idx] = v;
}

// Pass 1: each thread owns EIGHT consecutive P points (4 packed pairs);
// Q streams through SGPRs (s_load_dwordx4, fetched once per wave). 2-bank
// 8-Q chunks; compute per chunk = 448 cy of issue (2x R9) so s_load latency
// is fully covered before the lgkmcnt(0) drain.
template <int QSEGT>
__global__ __launch_bounds__(256) void chamfer_pass1(const f4* __restrict__ pk,
                                                     float* __restrict__ part) {
    constexpr int QLENT  = NPTS / QSEGT;
    constexpr int CHUNKS = QLENT / 8;         // even

    int qseg  = blockIdx.x & (QSEGT - 1);
    int chunk = blockIdx.x / QSEGT;           // 64 chunks of 2048 P points

    // block-uniform (from blockIdx only) -> SALU
    int grp   = chunk >> 1;                   // dir*16 + batch
    int dir   = grp >> 4;
    int bb    = grp & 15;

    int pidx0 = chunk * 2048 + threadIdx.x * 8;

    f4 p0 = pk[pidx0 + 0], p1 = pk[pidx0 + 1];
    f4 p2 = pk[pidx0 + 2], p3 = pk[pidx0 + 3];
    f4 p4 = pk[pidx0 + 4], p5 = pk[pidx0 + 5];
    f4 p6 = pk[pidx0 + 6], p7 = pk[pidx0 + 7];
    f2 px2a = {-2.0f * p0.x, -2.0f * p1.x}, px2b = {-2.0f * p2.x, -2.0f * p3.x};
    f2 py2a = {-2.0f * p0.y, -2.0f * p1.y}, py2b = {-2.0f * p2.y, -2.0f * p3.y};
    f2 pz2a = {-2.0f * p0.z, -2.0f * p1.z}, pz2b = {-2.0f * p2.z, -2.0f * p3.z};
    f2 px2c = {-2.0f * p4.x, -2.0f * p5.x}, px2d = {-2.0f * p6.x, -2.0f * p7.x};
    f2 py2c = {-2.0f * p4.y, -2.0f * p5.y}, py2d = {-2.0f * p6.y, -2.0f * p7.y};
    f2 pz2c = {-2.0f * p4.z, -2.0f * p5.z}, pz2d = {-2.0f * p6.z, -2.0f * p7.z};
    asm volatile("" :: "v"(px2a), "v"(py2a), "v"(pz2a),
                       "v"(px2b), "v"(py2b), "v"(pz2b),
                       "v"(px2c), "v"(py2c), "v"(pz2c),
                       "v"(px2d), "v"(py2d), "v"(pz2d));
    __builtin_amdgcn_sched_barrier(0);

    // uniform 64-bit Q base in SGPRs
    union { const f4* p; u32 w[2]; } pu;
    pu.p = pk + (1 - dir) * TOT + bb * NPTS + qseg * QLENT;
    u32 w0 = __builtin_amdgcn_readfirstlane(pu.w[0]);
    u32 w1 = __builtin_amdgcn_readfirstlane(pu.w[1]);
    u64 qb = ((u64)w1 << 32) | w0;

    float acc0 = 3.4e38f, acc1 = 3.4e38f, acc2 = 3.4e38f, acc3 = 3.4e38f;
    float acc4 = 3.4e38f, acc5 = 3.4e38f, acc6 = 3.4e38f, acc7 = 3.4e38f;

    f4 c0, c1, c2, c3, c4, c5, c6, c7;        // current bank (SGPRs)
    f4 n0, n1, n2, n3, n4, n5, n6, n7;        // next bank (SGPRs)

    SLOAD8(c0, c1, c2, c3, c4, c5, c6, c7);   // chunk 0
    LGKMW8(c0, c1, c2, c3, c4, c5, c6, c7);

    #pragma unroll 1
    for (int it = 0; it < (CHUNKS - 2) / 2; ++it) {
        SLOAD8(n0, n1, n2, n3, n4, n5, n6, n7);      // chunk 2it+1
        COMP8S(c0, c1, c2, c3, c4, c5, c6, c7);      // chunk 2it   (448 cy)
        LGKMW8(n0, n1, n2, n3, n4, n5, n6, n7);
        SLOAD8(c0, c1, c2, c3, c4, c5, c6, c7);      // chunk 2it+2
        COMP8S(n0, n1, n2, n3, n4, n5, n6, n7);      // chunk 2it+1
        LGKMW8(c0, c1, c2, c3, c4, c5, c6, c7);
    }
    SLOAD8(n0, n1, n2, n3, n4, n5, n6, n7);          // chunk CHUNKS-1
    COMP8S(c0, c1, c2, c3, c4, c5, c6, c7);          // chunk CHUNKS-2
    LGKMW8(n0, n1, n2, n3, n4, n5, n6, n7);
    COMP8S(n0, n1, n2, n3, n4, n5, n6, n7);          // chunk CHUNKS-1

    f4 lo = {acc0, acc1, acc2, acc3};
    f4 hi = {acc4, acc5, acc6, acc7};
    f4* dst = (f4*)(part + qseg * TWOTOT + pidx0);
    dst[0] = lo;
    dst[1] = hi;
}

// Pass 2: 4 points per thread, f4 loads of the partials, add |p|^2,
// block-reduce, one atomic per block.
__global__ __launch_bounds__(256) void chamfer_pass2(const f4* __restrict__ part4,
                                                     const float* __restrict__ pkf,
                                                     float* __restrict__ out,
                                                     int nseg) {
    int t4  = blockIdx.x * 256 + threadIdx.x;     // 0..TWOTOT/4-1
    f4 m = part4[t4];
    for (int s = 1; s < nseg; ++s) {
        f4 v = part4[s * (TWOTOT / 4) + t4];
        m.x = fminf(m.x, v.x); m.y = fminf(m.y, v.y);
        m.z = fminf(m.z, v.z); m.w = fminf(m.w, v.w);
    }
    int gid = t4 * 4;
    float r = (m.x + pkf[(gid + 0) * 4 + 3]) + (m.y + pkf[(gid + 1) * 4 + 3])
            + (m.z + pkf[(gid + 2) * 4 + 3]) + (m.w + pkf[(gid + 3) * 4 + 3]);

    float s = r;
    #pragma unroll
    for (int off = 32; off; off >>= 1) s += __shfl_down(s, off);
    __shared__ float red[4];
    int lane = threadIdx.x & 63, wid = threadIdx.x >> 6;
    if (lane == 0) red[wid] = s;
    __syncthreads();
    if (threadIdx.x == 0) {
        float tot = (red[0] + red[1]) + (red[2] + red[3]);
        atomicAdd(out, tot * (1.0f / (float)TOT));
    }
}

// ---------------- fallback (no workspace): direct form ----------------
__global__ __launch_bounds__(256) void chamfer_direct(const float* __restrict__ x,
                                                      const float* __restrict__ y,
                                                      float* __restrict__ out) {
    int blk   = blockIdx.x;
    int dir   = blk >> 8;
    int t     = blk & 255;
    int b     = t >> 4;
    int chunk = t & 15;

    const float* __restrict__ P = (dir ? y : x) + (b * NPTS + chunk * 256) * 3;
    const float* __restrict__ Q = (dir ? x : y) + b * NPTS * 3;

    float px = P[threadIdx.x * 3 + 0];
    float py = P[threadIdx.x * 3 + 1];
    float pz = P[threadIdx.x * 3 + 2];

    float b0 = 3.4e38f, b1 = 3.4e38f, b2 = 3.4e38f, b3 = 3.4e38f;
    for (int j = 0; j < NPTS; j += 4) {
        #pragma unroll
        for (int u = 0; u < 4; ++u) {
            float dx = px - Q[(j + u) * 3 + 0];
            float dy = py - Q[(j + u) * 3 + 1];
            float dz = pz - Q[(j + u) * 3 + 2];
            float d  = fmaf(dx, dx, fmaf(dy, dy, dz * dz));
            if (u == 0) b0 = fminf(b0, d);
            if (u == 1) b1 = fminf(b1, d);
            if (u == 2) b2 = fminf(b2, d);
            if (u == 3) b3 = fminf(b3, d);
        }
    }
    float best = fminf(fminf(b0, b1), fminf(b2, b3));

    float v = best;
    #pragma unroll
    for (int off = 32; off; off >>= 1) v += __shfl_down(v, off);
    __shared__ float red[4];
    int lane = threadIdx.x & 63, wid = threadIdx.x >> 6;
    if (lane == 0) red[wid] = v;
    __syncthreads();
    if (threadIdx.x == 0) {
        float s = (red[0] + red[1]) + (red[2] + red[3]);
        atomicAdd(out, s * (1.0f / (float)TOT));
    }
}

__global__ void zero_kernel(float* out) { out[0] = 0.0f; }

extern "C" void kernel_launch(void* const* d_in, const int* in_sizes, int n_in,
                              void* d_out, int out_size, void* d_ws, size_t ws_size,
                              hipStream_t stream) {
    const float* x = (const float*)d_in[0];
    const float* y = (const float*)d_in[1];
    float* out = (float*)d_out;

    size_t pk_bytes = (size_t)TWOTOT * 4 * sizeof(float);         // 2 MiB
    auto part_bytes = [&](int qseg) { return (size_t)qseg * TWOTOT * sizeof(float); };

    if (ws_size >= pk_bytes + part_bytes(16)) {
        // QSEG = 16 : grid 1024 (4 blocks/CU), part 8 MiB
        float* pkf  = (float*)d_ws;
        float* part = (float*)((char*)d_ws + pk_bytes);
        hipLaunchKernelGGL(pack_kernel, dim3(TWOTOT / 256), dim3(256), 0, stream,
                           x, y, (f4*)pkf, out);
        hipLaunchKernelGGL((chamfer_pass1<16>), dim3(64 * 16), dim3(256), 0, stream,
                           (const f4*)pkf, part);
        hipLaunchKernelGGL(chamfer_pass2, dim3(TWOTOT / 4 / 256), dim3(256), 0, stream,
                           (const f4*)part, pkf, out, 16);
    } else if (ws_size >= pk_bytes + part_bytes(8)) {
        // QSEG = 8 : grid 512, part 4 MiB
        float* pkf  = (float*)d_ws;
        float* part = (float*)((char*)d_ws + pk_bytes);
        hipLaunchKernelGGL(pack_kernel, dim3(TWOTOT / 256), dim3(256), 0, stream,
                           x, y, (f4*)pkf, out);
        hipLaunchKernelGGL((chamfer_pass1<8>), dim3(64 * 8), dim3(256), 0, stream,
                           (const f4*)pkf, part);
        hipLaunchKernelGGL(chamfer_pass2, dim3(TWOTOT / 4 / 256), dim3(256), 0, stream,
                           (const f4*)part, pkf, out, 8);
    } else if (ws_size >= pk_bytes + part_bytes(4)) {
        // QSEG = 4 : grid 256, part 2 MiB
        float* pkf  = (float*)d_ws;
        float* part = (float*)((char*)d_ws + pk_bytes);
        hipLaunchKernelGGL(pack_kernel, dim3(TWOTOT / 256), dim3(256), 0, stream,
                           x, y, (f4*)pkf, out);
        hipLaunchKernelGGL((chamfer_pass1<4>), dim3(64 * 4), dim3(256), 0, stream,
                           (const f4*)pkf, part);
        hipLaunchKernelGGL(chamfer_pass2, dim3(TWOTOT / 4 / 256), dim3(256), 0, stream,
                           (const f4*)part, pkf, out, 4);
    } else {
        hipLaunchKernelGGL(zero_kernel, dim3(1), dim3(1), 0, stream, out);
        hipLaunchKernelGGL(chamfer_direct, dim3(512), dim3(256), 0, stream, x, y, out);
    }
}